// Round 2
// baseline (1111.790 us; speedup 1.0000x reference)
//
#include <hip/hip_runtime.h>

// Pipeline:
//  1. split_x:          x f32 [4096,1024] -> x_hi, x_lo bf16
//  2. transpose_split:  w_qkv f32 [1024,3072] -> w_hi_t, w_lo_t bf16 [3072,1024] (N-major)
//  3. transpose_split:  w_out f32 [1024,1024] -> w_out_t bf16 [1024,1024]
//  4. gemm_qkv:   3-term split GEMM (K_eff=3072) with FUSED RoPE epilogue:
//                 Q (x8 score scale) and K -> hi/lo bf16 [B,H,S,128]; V -> bf16 [B,H,S,64]
//  5. flash:      causal online-softmax attention, 3-term QK^T, bf16 PV -> attn bf16 [4096,1024]
//  6. gemm_out:   attn @ w_out_t + b_out -> f32 d_out
//
// Workspace (70 MiB, non-overlapping in time):
//  [0,8)   xhi   (dead after gemm_qkv; reused as att)
//  [8,16)  xlo   (dead after gemm_qkv)
//  [16,22) whi   [22,28) wlo   [28,30) wot
//  [30,46) Qs    [46,62) Ks    [62,70) V

typedef __attribute__((ext_vector_type(8))) short s16x8;
typedef __attribute__((ext_vector_type(8))) unsigned short u16x8;
typedef __attribute__((ext_vector_type(4))) float f32x4;
typedef __attribute__((ext_vector_type(4))) int i32x4;

#define L2E 1.44269504088896340736f

__device__ __forceinline__ unsigned short f2bf(float f) {
  unsigned int u = __builtin_bit_cast(unsigned int, f);
  u += 0x7FFFu + ((u >> 16) & 1u);
  return (unsigned short)(u >> 16);
}
__device__ __forceinline__ float bf2f(unsigned short h) {
  unsigned int u = ((unsigned int)h) << 16;
  return __builtin_bit_cast(float, u);
}

__device__ __forceinline__ void gload16(const void* g, void* l) {
  __builtin_amdgcn_global_load_lds(
      (const __attribute__((address_space(1))) unsigned int*)g,
      (__attribute__((address_space(3))) unsigned int*)l, 16, 0, 0);
}

// ---------------- 1. split x into hi/lo bf16 ----------------
__global__ __launch_bounds__(256) void split_x_kernel(
    const float* __restrict__ x, unsigned short* __restrict__ xhi,
    unsigned short* __restrict__ xlo) {
  size_t i = ((size_t)blockIdx.x * 256 + threadIdx.x) * 8;
  f32x4 a = *(const f32x4*)(x + i);
  f32x4 c = *(const f32x4*)(x + i + 4);
  u16x8 h, lo;
#pragma unroll
  for (int j = 0; j < 4; ++j) {
    unsigned short hv = f2bf(a[j]);
    h[j] = hv; lo[j] = f2bf(a[j] - bf2f(hv));
    unsigned short hv2 = f2bf(c[j]);
    h[4 + j] = hv2; lo[4 + j] = f2bf(c[j] - bf2f(hv2));
  }
  *(u16x8*)(xhi + i) = h;
  *(u16x8*)(xlo + i) = lo;
}

// ---------------- 2/3. transpose + split weights ----------------
// W [1024 x N] f32 (K-major) -> Thi/Tlo [N x 1024] bf16 (N-major)
__global__ __launch_bounds__(256) void transpose_split_kernel(
    const float* __restrict__ W, unsigned short* __restrict__ Thi,
    unsigned short* __restrict__ Tlo, int N, int hasLo) {
  __shared__ unsigned short hi[64][72];
  __shared__ unsigned short lo[64][72];
  const int t = threadIdx.x;
  const int k0 = blockIdx.x * 64, n0 = blockIdx.y * 64;
#pragma unroll
  for (int r = 0; r < 16; ++r) {
    int kk = r * 4 + (t >> 6);
    int nn = t & 63;
    float v = W[(size_t)(k0 + kk) * N + n0 + nn];
    unsigned short hv = f2bf(v);
    hi[nn][kk] = hv;
    lo[nn][kk] = f2bf(v - bf2f(hv));
  }
  __syncthreads();
#pragma unroll
  for (int i = 0; i < 2; ++i) {
    int ci = t + i * 256;
    int nn = ci >> 3, kc = (ci & 7) * 8;
    u16x8 vh, vl;
#pragma unroll
    for (int j = 0; j < 8; ++j) { vh[j] = hi[nn][kc + j]; vl[j] = lo[nn][kc + j]; }
    *(u16x8*)(Thi + (size_t)(n0 + nn) * 1024 + k0 + kc) = vh;
    if (hasLo) *(u16x8*)(Tlo + (size_t)(n0 + nn) * 1024 + k0 + kc) = vl;
  }
}

// ---------------- 4. QKV GEMM (split 3-term) + fused RoPE epilogue ----------------
__global__ __launch_bounds__(256) void gemm_qkv_kernel(
    const unsigned short* __restrict__ xhi, const unsigned short* __restrict__ xlo,
    const unsigned short* __restrict__ whi, const unsigned short* __restrict__ wlo,
    const float* __restrict__ bqkv, unsigned short* __restrict__ Qsb,
    unsigned short* __restrict__ Ksb, unsigned short* __restrict__ vbuf) {
  __shared__ alignas(16) unsigned short As[128 * 64];
  __shared__ alignas(16) unsigned short Bs[128 * 64];
  const int tid = threadIdx.x, w = tid >> 6, l = tid & 63;
  const int l15 = l & 15, l4 = l >> 4;
  const int m0 = blockIdx.x * 128, n0 = blockIdx.y * 128;
  const int wrow = w >> 1, wcol = w & 1;
  const int srow = l >> 3, scol = (l & 7) * 8;

  f32x4 acc[4][4] = {};

  for (int kt = 0; kt < 48; ++kt) {
    int k0 = kt * 64;
    const unsigned short *Asrc, *Bsrc;
    int kk;
    if (k0 < 1024)       { Asrc = xhi; Bsrc = whi; kk = k0; }
    else if (k0 < 2048)  { Asrc = xhi; Bsrc = wlo; kk = k0 - 1024; }
    else                 { Asrc = xlo; Bsrc = whi; kk = k0 - 2048; }
#pragma unroll
    for (int i = 0; i < 4; ++i) {
      int ci = w * 4 + i;
      int row = ci * 8 + srow;
      gload16(Asrc + (size_t)(m0 + row) * 1024 + kk + scol, (char*)As + ci * 1024);
      gload16(Bsrc + (size_t)(n0 + row) * 1024 + kk + scol, (char*)Bs + ci * 1024);
    }
    __syncthreads();
#pragma unroll
    for (int ks = 0; ks < 2; ++ks) {
      s16x8 af[4], bfr[4];
#pragma unroll
      for (int g = 0; g < 4; ++g) {
        af[g] = *(const s16x8*)(As + (wrow * 64 + g * 16 + l15) * 64 + ks * 32 + l4 * 8);
        bfr[g] = *(const s16x8*)(Bs + (wcol * 64 + g * 16 + l15) * 64 + ks * 32 + l4 * 8);
      }
#pragma unroll
      for (int rg = 0; rg < 4; ++rg)
#pragma unroll
        for (int cg = 0; cg < 4; ++cg)
          acc[rg][cg] = __builtin_amdgcn_mfma_f32_16x16x32_bf16(af[rg], bfr[cg], acc[rg][cg], 0, 0, 0);
    }
    __syncthreads();
  }

  // epilogue: n < 2048 -> RoPE (Q scaled x8) -> hi/lo bf16 split; n >= 2048 -> V bf16
#pragma unroll
  for (int cg = 0; cg < 4; ++cg) {
    int n = n0 + wcol * 64 + cg * 16 + l15;
    float bias = bqkv[n];
    int which = n >> 10;           // block-uniform (n0 multiple of 128)
    int col = n & 1023;
    int hh = col >> 6, dk = col & 63;
    if (which == 2) {
#pragma unroll
      for (int rg = 0; rg < 4; ++rg)
#pragma unroll
        for (int r = 0; r < 4; ++r) {
          int m = m0 + wrow * 64 + rg * 16 + l4 * 4 + r;
          int bb = m >> 11, s = m & 2047;
          float v = acc[rg][cg][r] + bias;
          vbuf[(((size_t)bb * 16 + hh) * 2048 + s) * 64 + dk] = f2bf(v);
        }
    } else {
      // RoPE: pair partner (dk^1) sits in lane l^1 (same reg index)
      float invf = exp2f(-(float)(dk >> 1) * 0.4152410118609203f);  // 10000^(-(dk/2)/32)
      unsigned short* dst0 = (which ? Ksb : Qsb);
#pragma unroll
      for (int rg = 0; rg < 4; ++rg)
#pragma unroll
        for (int r = 0; r < 4; ++r) {
          int m = m0 + wrow * 64 + rg * 16 + l4 * 4 + r;
          int bb = m >> 11, s = m & 2047;
          float v = acc[rg][cg][r] + bias;
          float p = __shfl_xor(v, 1);
          float ang = (float)s * invf;
          float sn, cs;
          sincosf(ang, &sn, &cs);
          // even dk: x1=v, x2=p -> x1*cos - x2*sin ; odd dk: x1=p, x2=v -> x1*sin + x2*cos
          float rr = (dk & 1) ? (p * sn + v * cs) : (v * cs - p * sn);
          if (which == 0) rr *= 8.0f;  // fold score scale sqrt(dk)=8 into Q
          unsigned short hv = f2bf(rr);
          unsigned short lv = f2bf(rr - bf2f(hv));
          unsigned short* dst = dst0 + (((size_t)bb * 16 + hh) * 2048 + s) * 128;
          dst[dk] = hv;
          dst[64 + dk] = lv;
        }
    }
  }
}

// ---------------- 5. causal flash attention ----------------
__global__ __launch_bounds__(256) void flash_kernel(
    const unsigned short* __restrict__ Qs, const unsigned short* __restrict__ Ks,
    const unsigned short* __restrict__ Vb, unsigned short* __restrict__ attn) {
  __shared__ alignas(16) unsigned short Khi[64 * 64];
  __shared__ alignas(16) unsigned short Klo[64 * 64];
  __shared__ alignas(16) unsigned short Vt[64 * 64];
  __shared__ alignas(16) unsigned short Pl[4][32 * 64];

  const int tid = threadIdx.x;
  const int wv = tid >> 6, l = tid & 63;
  const int l15 = l & 15, l4 = l >> 4;
  const int qb = blockIdx.x * 128;
  const int h = blockIdx.y, b = blockIdx.z;

  const size_t bh = (size_t)(b * 16 + h);
  const unsigned short* Qbase = Qs + bh * 2048 * 128;
  const unsigned short* Kbase = Ks + bh * 2048 * 128;
  const unsigned short* Vbase = Vb + bh * 2048 * 64;

  s16x8 qf[2][2][2];  // [rowgroup][hi/lo][ks]
#pragma unroll
  for (int rg = 0; rg < 2; ++rg) {
    int q = qb + wv * 32 + rg * 16 + l15;
    const unsigned short* qr = Qbase + (size_t)q * 128;
#pragma unroll
    for (int ks = 0; ks < 2; ++ks) {
      qf[rg][0][ks] = *(const s16x8*)(qr + ks * 32 + l4 * 8);
      qf[rg][1][ks] = *(const s16x8*)(qr + 64 + ks * 32 + l4 * 8);
    }
  }

  f32x4 acc[2][4] = {};
  float mrow[2][4], lrow[2][4];
#pragma unroll
  for (int rg = 0; rg < 2; ++rg)
#pragma unroll
    for (int r = 0; r < 4; ++r) { mrow[rg][r] = -1e38f; lrow[rg][r] = 0.f; }

  const int nt = (qb >> 6) + 2;
  for (int kt = 0; kt < nt; ++kt) {
    const int kv0 = kt * 64;
    // stage K hi/lo (XOR-swizzled rows)
#pragma unroll
    for (int i = 0; i < 2; ++i) {
      int ci = tid + i * 256;
      int row = ci >> 3, cb = (ci & 7) * 16;
      const char* src = (const char*)(Kbase + (size_t)(kv0 + row) * 128);
      i32x4 dhi = *(const i32x4*)(src + cb);
      i32x4 dlo = *(const i32x4*)(src + 128 + cb);
      int sw = cb ^ ((row & 7) << 4);
      *(i32x4*)((char*)Khi + row * 128 + sw) = dhi;
      *(i32x4*)((char*)Klo + row * 128 + sw) = dlo;
    }
    // stage V transposed (Vt[d][kv], swizzled)
#pragma unroll
    for (int i = 0; i < 2; ++i) {
      int ci = tid + i * 256;
      int vr = ci >> 3, d0 = (ci & 7) * 8;
      u16x8 vv = *(const u16x8*)(Vbase + (size_t)(kv0 + vr) * 64 + d0);
#pragma unroll
      for (int j = 0; j < 8; ++j) {
        int d = d0 + j;
        int addr = d * 128 + ((vr * 2) ^ ((d & 7) << 4));
        *(unsigned short*)((char*)Vt + addr) = vv[j];
      }
    }
    __syncthreads();

    // S = (8 Q_roped) K_roped^T : 3-term split product
    f32x4 sc[2][4];
    {
      s16x8 kbh[4][2], kbl[4][2];
#pragma unroll
      for (int cg = 0; cg < 4; ++cg) {
        int kr = cg * 16 + l15;
        int swz = (kr & 7) << 4;
        const char* ph = (const char*)Khi + kr * 128;
        const char* pl2 = (const char*)Klo + kr * 128;
#pragma unroll
        for (int ks = 0; ks < 2; ++ks) {
          int off = (ks * 64 + l4 * 16) ^ swz;
          kbh[cg][ks] = *(const s16x8*)(ph + off);
          kbl[cg][ks] = *(const s16x8*)(pl2 + off);
        }
      }
#pragma unroll
      for (int rg = 0; rg < 2; ++rg)
#pragma unroll
        for (int cg = 0; cg < 4; ++cg) {
          f32x4 a = {0.f, 0.f, 0.f, 0.f};
#pragma unroll
          for (int ks = 0; ks < 2; ++ks) {
            a = __builtin_amdgcn_mfma_f32_16x16x32_bf16(qf[rg][0][ks], kbh[cg][ks], a, 0, 0, 0);
            a = __builtin_amdgcn_mfma_f32_16x16x32_bf16(qf[rg][0][ks], kbl[cg][ks], a, 0, 0, 0);
            a = __builtin_amdgcn_mfma_f32_16x16x32_bf16(qf[rg][1][ks], kbh[cg][ks], a, 0, 0, 0);
          }
          sc[rg][cg] = a;
        }
    }

    // causal mask (only diagonal-crossing tiles)
    if (kt >= (qb >> 6)) {
#pragma unroll
      for (int rg = 0; rg < 2; ++rg)
#pragma unroll
        for (int cg = 0; cg < 4; ++cg)
#pragma unroll
          for (int r = 0; r < 4; ++r) {
            int q = qb + wv * 32 + rg * 16 + l4 * 4 + r;
            int kv = kv0 + cg * 16 + l15;
            if (kv > q) sc[rg][cg][r] = -1e38f;
          }
    }

    // online softmax
#pragma unroll
    for (int rg = 0; rg < 2; ++rg) {
      float pm[4], al[4], rs[4];
#pragma unroll
      for (int r = 0; r < 4; ++r) {
        float v = fmaxf(fmaxf(sc[rg][0][r], sc[rg][1][r]), fmaxf(sc[rg][2][r], sc[rg][3][r]));
        v = fmaxf(v, __shfl_xor(v, 1));
        v = fmaxf(v, __shfl_xor(v, 2));
        v = fmaxf(v, __shfl_xor(v, 4));
        v = fmaxf(v, __shfl_xor(v, 8));
        float mn = fmaxf(mrow[rg][r], v);
        al[r] = exp2f((mrow[rg][r] - mn) * L2E);
        mrow[rg][r] = mn;
        pm[r] = mn;
        rs[r] = 0.f;
      }
#pragma unroll
      for (int cg = 0; cg < 4; ++cg)
#pragma unroll
        for (int r = 0; r < 4; ++r) {
          float p = exp2f((sc[rg][cg][r] - pm[r]) * L2E);
          sc[rg][cg][r] = p;
          rs[r] += p;
        }
#pragma unroll
      for (int r = 0; r < 4; ++r) {
        float v = rs[r];
        v += __shfl_xor(v, 1);
        v += __shfl_xor(v, 2);
        v += __shfl_xor(v, 4);
        v += __shfl_xor(v, 8);
        lrow[rg][r] = lrow[rg][r] * al[r] + v;
      }
#pragma unroll
      for (int dg = 0; dg < 4; ++dg)
#pragma unroll
        for (int r = 0; r < 4; ++r) acc[rg][dg][r] *= al[r];
      // write P (bf16) to per-wave LDS, swizzled
#pragma unroll
      for (int cg = 0; cg < 4; ++cg)
#pragma unroll
        for (int r = 0; r < 4; ++r) {
          int roww = rg * 16 + l4 * 4 + r;
          int colb = (cg * 16 + l15) * 2;
          int addr = roww * 128 + (colb ^ ((roww & 7) << 4));
          *(unsigned short*)((char*)Pl[wv] + addr) = f2bf(sc[rg][cg][r]);
        }
    }
    __syncthreads();

    // O += P V
    {
      s16x8 pf[2][2];
#pragma unroll
      for (int rg = 0; rg < 2; ++rg) {
        int pr = rg * 16 + l15;
        int swz = (pr & 7) << 4;
#pragma unroll
        for (int kc = 0; kc < 2; ++kc)
          pf[rg][kc] = *(const s16x8*)((const char*)Pl[wv] + pr * 128 + ((kc * 64 + l4 * 16) ^ swz));
      }
#pragma unroll
      for (int dg = 0; dg < 4; ++dg) {
        int dr = dg * 16 + l15;
        int swz = (dr & 7) << 4;
#pragma unroll
        for (int kc = 0; kc < 2; ++kc) {
          s16x8 vf = *(const s16x8*)((const char*)Vt + dr * 128 + ((kc * 64 + l4 * 16) ^ swz));
#pragma unroll
          for (int rg = 0; rg < 2; ++rg)
            acc[rg][dg] = __builtin_amdgcn_mfma_f32_16x16x32_bf16(pf[rg][kc], vf, acc[rg][dg], 0, 0, 0);
        }
      }
    }
    __syncthreads();
  }

  // epilogue: O /= l, write bf16 concat layout [B,S,H*64]
#pragma unroll
  for (int rg = 0; rg < 2; ++rg) {
#pragma unroll
    for (int r = 0; r < 4; ++r) {
      float inv = 1.0f / lrow[rg][r];
      int q = qb + wv * 32 + rg * 16 + l4 * 4 + r;
      size_t base = ((size_t)(b * 2048 + q)) * 1024 + h * 64;
#pragma unroll
      for (int dg = 0; dg < 4; ++dg)
        attn[base + dg * 16 + l15] = f2bf(acc[rg][dg][r] * inv);
    }
  }
}

// ---------------- 6. output projection ----------------
__global__ __launch_bounds__(256) void gemm_out_kernel(
    const unsigned short* __restrict__ attn, const unsigned short* __restrict__ wot,
    const float* __restrict__ bout, float* __restrict__ out) {
  __shared__ alignas(16) unsigned short As[128 * 64];
  __shared__ alignas(16) unsigned short Bs[128 * 64];
  const int tid = threadIdx.x, w = tid >> 6, l = tid & 63;
  const int l15 = l & 15, l4 = l >> 4;
  const int m0 = blockIdx.x * 128, n0 = blockIdx.y * 128;
  const int wrow = w >> 1, wcol = w & 1;
  const int srow = l >> 3, scol = (l & 7) * 8;

  f32x4 acc[4][4] = {};

  for (int kt = 0; kt < 16; ++kt) {
    int k0 = kt * 64;
#pragma unroll
    for (int i = 0; i < 4; ++i) {
      int ci = w * 4 + i;
      int row = ci * 8 + srow;
      gload16(attn + (size_t)(m0 + row) * 1024 + k0 + scol, (char*)As + ci * 1024);
      gload16(wot + (size_t)(n0 + row) * 1024 + k0 + scol, (char*)Bs + ci * 1024);
    }
    __syncthreads();
#pragma unroll
    for (int ks = 0; ks < 2; ++ks) {
      s16x8 af[4], bfr[4];
#pragma unroll
      for (int g = 0; g < 4; ++g) {
        af[g] = *(const s16x8*)(As + (wrow * 64 + g * 16 + l15) * 64 + ks * 32 + l4 * 8);
        bfr[g] = *(const s16x8*)(Bs + (wcol * 64 + g * 16 + l15) * 64 + ks * 32 + l4 * 8);
      }
#pragma unroll
      for (int rg = 0; rg < 4; ++rg)
#pragma unroll
        for (int cg = 0; cg < 4; ++cg)
          acc[rg][cg] = __builtin_amdgcn_mfma_f32_16x16x32_bf16(af[rg], bfr[cg], acc[rg][cg], 0, 0, 0);
    }
    __syncthreads();
  }

#pragma unroll
  for (int cg = 0; cg < 4; ++cg) {
    int n = n0 + wcol * 64 + cg * 16 + l15;
    float bias = bout[n];
#pragma unroll
    for (int rg = 0; rg < 4; ++rg) {
#pragma unroll
      for (int r = 0; r < 4; ++r) {
        int m = m0 + wrow * 64 + rg * 16 + l4 * 4 + r;
        out[(size_t)m * 1024 + n] = acc[rg][cg][r] + bias;
      }
    }
  }
}

// ---------------- workspace layout (bytes), total 70 MiB ----------------
#define OFF_XHI 0ull               // 8 MiB   (dead after gemm_qkv)
#define OFF_ATT 0ull               // 8 MiB   (aliases XHI; written by flash)
#define OFF_XLO 8388608ull         // 8 MiB   (dead after gemm_qkv)
#define OFF_WHI 16777216ull        // 6 MiB
#define OFF_WLO 23068672ull        // 6 MiB
#define OFF_WOT 29360128ull        // 2 MiB
#define OFF_QS  31457280ull        // 16 MiB
#define OFF_KS  48234496ull        // 16 MiB
#define OFF_V   65011712ull        // 8 MiB -> ends at 73400320

extern "C" void kernel_launch(void* const* d_in, const int* in_sizes, int n_in,
                              void* d_out, int out_size, void* d_ws, size_t ws_size,
                              hipStream_t stream) {
  (void)in_sizes; (void)n_in; (void)out_size; (void)ws_size;
  const float* x     = (const float*)d_in[0];
  const float* w_qkv = (const float*)d_in[1];
  const float* b_qkv = (const float*)d_in[2];
  const float* w_out = (const float*)d_in[3];
  const float* b_out = (const float*)d_in[4];
  float* out = (float*)d_out;
  char* ws = (char*)d_ws;

  unsigned short* xhi = (unsigned short*)(ws + OFF_XHI);
  unsigned short* xlo = (unsigned short*)(ws + OFF_XLO);
  unsigned short* whi = (unsigned short*)(ws + OFF_WHI);
  unsigned short* wlo = (unsigned short*)(ws + OFF_WLO);
  unsigned short* wot = (unsigned short*)(ws + OFF_WOT);
  unsigned short* Qsb = (unsigned short*)(ws + OFF_QS);
  unsigned short* Ksb = (unsigned short*)(ws + OFF_KS);
  unsigned short* vbf = (unsigned short*)(ws + OFF_V);
  unsigned short* att = (unsigned short*)(ws + OFF_ATT);

  split_x_kernel<<<2048, 256, 0, stream>>>(x, xhi, xlo);
  transpose_split_kernel<<<dim3(16, 48), 256, 0, stream>>>(w_qkv, whi, wlo, 3072, 1);
  transpose_split_kernel<<<dim3(16, 16), 256, 0, stream>>>(w_out, wot, nullptr, 1024, 0);
  gemm_qkv_kernel<<<dim3(32, 24), 256, 0, stream>>>(xhi, xlo, whi, wlo, b_qkv, Qsb, Ksb, vbf);
  flash_kernel<<<dim3(16, 16, 2), 256, 0, stream>>>(Qsb, Ksb, vbf, att);
  gemm_out_kernel<<<dim3(32, 8), 256, 0, stream>>>(att, wot, b_out, out);
}